// Round 11
// baseline (206.385 us; speedup 1.0000x reference)
//
#include <hip/hip_runtime.h>
#include <hip/hip_bf16.h>

#define D_IN  128
#define D_HID 256
#define CBITS 7
#define CSIZE 128          // nodes per bucket (one refine_gather block)
#define EPB   4096         // edges per coarse_bin block
#define CCAP  4096         // entry capacity per bucket (mean 2048, +many sigma)

typedef __bf16 bf16x8 __attribute__((ext_vector_type(8)));
typedef float  f32x4  __attribute__((ext_vector_type(4)));
typedef float  f32x2  __attribute__((ext_vector_type(2)));

__device__ __forceinline__ unsigned short f2bf(float f) {
    unsigned u = __float_as_uint(f);
    u += 0x7FFFu + ((u >> 16) & 1u);   // RNE
    return (unsigned short)(u >> 16);
}
__device__ __forceinline__ uint2 pack4(float4 v) {
    unsigned lo = (unsigned)f2bf(v.x) | ((unsigned)f2bf(v.y) << 16);
    unsigned hi = (unsigned)f2bf(v.z) | ((unsigned)f2bf(v.w) << 16);
    return make_uint2(lo, hi);
}
// pack 4 floats -> 4 fp8 e4m3 bytes (HW cvt)
__device__ __forceinline__ unsigned packfp8(float4 v) {
    int u = __builtin_amdgcn_cvt_pk_fp8_f32(v.x, v.y, 0, false);
    u = __builtin_amdgcn_cvt_pk_fp8_f32(v.z, v.w, u, true);
    return (unsigned)u;
}
// async 16B global -> LDS (vmcnt)
__device__ __forceinline__ void g2lds16(const void* g, void* l) {
    __builtin_amdgcn_global_load_lds(
        (const __attribute__((address_space(1))) unsigned int*)g,
        (__attribute__((address_space(3))) unsigned int*)l, 16, 0, 0);
}
// accumulate 16 fp8 channels (one uint4) into 8 packed f32x2 accumulators
__device__ __forceinline__ void acc16(f32x2* a, uint4 v) {
    a[0] += __builtin_amdgcn_cvt_pk_f32_fp8(v.x, false);
    a[1] += __builtin_amdgcn_cvt_pk_f32_fp8(v.x, true);
    a[2] += __builtin_amdgcn_cvt_pk_f32_fp8(v.y, false);
    a[3] += __builtin_amdgcn_cvt_pk_f32_fp8(v.y, true);
    a[4] += __builtin_amdgcn_cvt_pk_f32_fp8(v.z, false);
    a[5] += __builtin_amdgcn_cvt_pk_f32_fp8(v.z, true);
    a[6] += __builtin_amdgcn_cvt_pk_f32_fp8(v.w, false);
    a[7] += __builtin_amdgcn_cvt_pk_f32_fp8(v.w, true);
}

// FUSED prep + coarse_bin. Binning blocks FIRST ([0,NB1)); converts fill the
// rest. Convert branch is WAVE-CONTIGUOUS: thread handles 8 float4 chunks at
// stride 512 (idx = base + k*512 + tid) so every load instruction is
// lane-contiguous (1 KB/wave, minimal cache-line touches) -- round 10's
// 4-consecutive-float4-per-thread layout had 64-B lane stride = 4x the
// line-touch rate and throttled the stream to 2.35 TB/s. Stores likewise
// wave-contiguous (uint2 bf16 + uint fp8). Scan is wave-level shfl (round 10).
__global__ __launch_bounds__(512)
void prep_bin(const float* __restrict__ x, unsigned short* __restrict__ xb,
              unsigned char* __restrict__ x8,
              const float* __restrict__ Wr2, const float* __restrict__ Wl2,
              unsigned short* __restrict__ Bsw,
              const void* __restrict__ ei, int* __restrict__ gcur,
              unsigned* __restrict__ segc,
              long n4, int NB1, int E, int NCB) {
    __shared__ unsigned sorted[EPB];          // 16 KB
    __shared__ unsigned short bkt[EPB];       // 8 KB
    __shared__ int cnt[1024], scn[1024], cur[1024], gbase[1024];  // 16 KB
    __shared__ int wtot[8], woff[8];
    __shared__ int s_is64;
    const int bid = blockIdx.x;
    const int tid = threadIdx.x;

    if (bid >= NB1 + 16) {
        // ---- x -> bf16 (xb) + fp8 (x8): 8 wave-contiguous float4 chunks ----
        const long base = (long)(bid - NB1 - 16) * 4096;
        const float4* x4 = (const float4*)x;
        uint2* xb2 = (uint2*)xb;
        unsigned* x81 = (unsigned*)x8;
        #pragma unroll
        for (int k = 0; k < 8; ++k) {
            const long idx = base + k * 512 + tid;
            if (idx < n4) {
                const float4 v = x4[idx];
                xb2[idx] = pack4(v);
                x81[idx] = packfp8(v);
            }
        }
        return;
    }
    if (bid >= NB1) {
        // ---- B pack into MFMA-fragment order ----
        // Bsw[(((kk*4+wn2)*4+t)*64+lane)*8+e] = B[wn2*64+t*16+(lane&15)][kk*32+(lane>>4)*8+e]
        const int t_idx = (bid - NB1) * 512 + tid;
        const int lane = t_idx & 63;
        const int rest = t_idx >> 6;
        const int tt   = rest & 3;
        const int wn2  = (rest >> 2) & 3;
        const int kk   = rest >> 4;
        const int j = wn2 * 64 + tt * 16 + (lane & 15);
        const int k = kk * 32 + (lane >> 4) * 8;
        const float* src = (k < 128) ? &Wr2[j * 128 + k] : &Wl2[j * 128 + (k - 128)];
        float4 v0 = *(const float4*)src;
        float4 v1 = *(const float4*)(src + 4);
        uint2 p0 = pack4(v0), p1 = pack4(v1);
        *(uint4*)&Bsw[(long)t_idx * 8] = make_uint4(p0.x, p0.y, p1.x, p1.y);
        return;
    }

    // ---- coarse_bin: block-local counting sort (registers + LDS) ----
    const long e0 = (long)bid * EPB;
    const int ecnt = (int)min((long)EPB, (long)E - e0);

    if (tid < 64) {
        const int v = ((const int*)ei)[2 * tid + 1];
        const unsigned long long b = __ballot(v != 0);
        if (tid == 0) s_is64 = (b == 0ull);
    }
    for (int i = tid; i < 1024; i += 512) cnt[i] = 0;
    __syncthreads();
    const int is64 = s_is64;

    // load edges into registers + histogram
    int sv[8], tv[8];
    #pragma unroll
    for (int k = 0; k < 8; ++k) {
        const int j = tid + k * 512;
        if (j < ecnt) {
            if (is64) {
                sv[k] = (int)((const long long*)ei)[e0 + j];
                tv[k] = (int)((const long long*)ei)[E + e0 + j];
            } else {
                sv[k] = ((const int*)ei)[e0 + j];
                tv[k] = ((const int*)ei)[E + e0 + j];
            }
            atomicAdd(&cnt[tv[k] >> CBITS], 1);
        }
    }
    __syncthreads();   // histogram complete

    // global segment base per bucket (independent of scan -> overlaps it)
    for (int c = tid; c < NCB; c += 512)
        gbase[c] = cnt[c] ? atomicAdd(&gcur[c * 16], cnt[c]) : 0;

    // wave-level scan: wave wv owns counters [wv*128, wv*128+128), 2 per lane
    {
        const int wv = tid >> 6, ln = tid & 63;
        const int i0 = wv * 128 + ln * 2;
        const int c0 = cnt[i0], c1 = cnt[i0 + 1];
        const int pair = c0 + c1;
        int sc = pair;
        #pragma unroll
        for (int off = 1; off < 64; off <<= 1) {
            const int v = __shfl_up(sc, off);
            if (ln >= off) sc += v;
        }
        if (ln == 63) wtot[wv] = sc;
        __syncthreads();   // wtot ready (also covers gbase)
        if (tid == 0) {
            int s = 0;
            #pragma unroll
            for (int w = 0; w < 8; ++w) { woff[w] = s; s += wtot[w]; }
        }
        __syncthreads();
        const int ebase = woff[wv] + sc - pair;   // exclusive prefix of this pair
        cur[i0]     = ebase;                       // scatter cursors (exclusive)
        cur[i0 + 1] = ebase + c0;
        scn[i0]     = ebase + c0;                  // inclusive (run start = scn-cnt)
        scn[i0 + 1] = ebase + pair;
    }
    __syncthreads();

    // scatter into LDS sorted order
    #pragma unroll
    for (int k = 0; k < 8; ++k) {
        const int j = tid + k * 512;
        if (j < ecnt) {
            const int c = tv[k] >> CBITS;
            const int r = atomicAdd(&cur[c], 1);
            sorted[r] = ((unsigned)sv[k] << CBITS) | (unsigned)(tv[k] & (CSIZE - 1));
            bkt[r] = (unsigned short)c;
        }
    }
    __syncthreads();

    // streamed, run-coalesced write-out
    for (int i = tid; i < ecnt; i += 512) {
        const int c = bkt[i];
        const int pos = gbase[c] + (i - (scn[c] - cnt[c]));
        if (pos < CCAP) segc[(long)c * CCAP + pos] = sorted[i];
    }
}

// Stage 2+3 FUSED: per 128-node bucket (512 thr, 8 waves): histogram + WAVE-
// LEVEL scan (wave 0 shfl-scans all 128 counters; 1 barrier replaces ~15) +
// scatter build the node-ordered edge list IN LDS (order[]), then the gather
// consumes it in place. Wave = 8 node-slots x 8 lanes; each 8-lane group owns
// one node's full 128-B fp8 row (uint4/lane = 16 B); 4-edge unroll; dual
// accumulator sets split the packed-add chain. No cross-lane reduction.
// order[] entries: with CBITS=7, e & ~127 == src*128 == byte offset into x8.
__global__ __launch_bounds__(512)
void refine_gather(const int* __restrict__ gcur, const unsigned* __restrict__ segc,
                   const unsigned char* __restrict__ x8,
                   unsigned short* __restrict__ aggb, int M) {
    __shared__ unsigned order[CCAP];            // 16 KB (src byte offsets)
    __shared__ int degh[CSIZE], scn[CSIZE], cur[CSIZE];
    const int tid = threadIdx.x;
    const int cb = blockIdx.x;
    const int nbase = cb << CBITS;
    const int nn = min(CSIZE, M - nbase);
    const int len = min(gcur[cb * 16], CCAP);
    const unsigned* sp = segc + (long)cb * CCAP;

    if (tid < CSIZE) degh[tid] = 0;
    __syncthreads();
    for (int i = tid; i < len; i += 512) {
        const unsigned e = sp[i];
        atomicAdd(&degh[e & (CSIZE - 1)], 1);
    }
    __syncthreads();   // histogram complete

    // wave 0 shfl-scans the 128 counters (2 per lane)
    if (tid < 64) {
        const int i0 = tid * 2;
        const int c0 = degh[i0], c1 = degh[i0 + 1];
        const int pair = c0 + c1;
        int sc = pair;
        #pragma unroll
        for (int off = 1; off < 64; off <<= 1) {
            const int v = __shfl_up(sc, off);
            if (tid >= off) sc += v;
        }
        const int ebase = sc - pair;   // exclusive prefix of pair
        cur[i0]     = ebase;
        cur[i0 + 1] = ebase + c0;
        scn[i0]     = ebase + c0;      // inclusive
        scn[i0 + 1] = ebase + pair;
    }
    __syncthreads();

    for (int i = tid; i < len; i += 512) {
        const unsigned e = sp[i];
        const int r = atomicAdd(&cur[e & (CSIZE - 1)], 1);
        order[r] = e & ~(unsigned)(CSIZE - 1);   // src << 7 = byte offset into x8
    }
    __syncthreads();

    // ---- gather phase ----
    const int lane = tid & 63;
    const int wave = tid >> 6;       // 0..7
    const int ns   = lane >> 3;      // node slot 0..7
    const int c4   = lane & 7;       // uint4 column: channels c4*16 .. c4*16+15
    const unsigned chb = (unsigned)c4 * 16;

    for (int base = wave * 8; base < nn; base += 64) {
        const int nl = base + ns;
        int deg = 0, beg = 0;
        if (nl < nn) { deg = degh[nl]; beg = scn[nl] - deg; }
        f32x2 a[8] = {}, b[8] = {};
        int i = 0;
        for (; i + 4 <= deg; i += 4) {
            const unsigned o0 = order[beg + i];
            const unsigned o1 = order[beg + i + 1];
            const unsigned o2 = order[beg + i + 2];
            const unsigned o3 = order[beg + i + 3];
            uint4 v0 = *(const uint4*)(x8 + (o0 + chb));
            uint4 v1 = *(const uint4*)(x8 + (o1 + chb));
            uint4 v2 = *(const uint4*)(x8 + (o2 + chb));
            uint4 v3 = *(const uint4*)(x8 + (o3 + chb));
            acc16(a, v0); acc16(b, v1); acc16(a, v2); acc16(b, v3);
        }
        if (i < deg) {
            uint4 v = *(const uint4*)(x8 + (order[beg + i] + chb));
            acc16(a, v); ++i;
        }
        if (i < deg) {
            uint4 v = *(const uint4*)(x8 + (order[beg + i] + chb));
            acc16(b, v); ++i;
        }
        if (i < deg) {
            uint4 v = *(const uint4*)(x8 + (order[beg + i] + chb));
            acc16(a, v); ++i;
        }
        if (nl < nn) {
            const float rdiv = 1.0f / fmaxf((float)deg, 1.0f);
            unsigned w[8];
            #pragma unroll
            for (int j = 0; j < 8; ++j) {
                const f32x2 s = a[j] + b[j];
                w[j] = (unsigned)f2bf(s.x * rdiv) | ((unsigned)f2bf(s.y * rdiv) << 16);
            }
            unsigned short* dst = aggb + (long)(nbase + nl) * 128 + c4 * 16;
            *(uint4*)dst       = make_uint4(w[0], w[1], w[2], w[3]);
            *(uint4*)(dst + 8) = make_uint4(w[4], w[5], w[6], w[7]);
        }
    }
}

// GEMM v4: T3+T4 pipelined M-loop, 512 resident blocks (2/CU), 4-deep LDS ring
// (4 x 16 KB = 64 KB), counted s_waitcnt vmcnt (never 0 in steady state), ONE
// raw s_barrier per tile, B + bias hoisted to registers once per block, pool
// accumulated in registers with a single atomic flush. NO in-kernel grid sync
// (round 7: per-block __threadfence + done-counter cost ~25us).
__global__ __launch_bounds__(256, 2)
void gemm_pool(const unsigned short* __restrict__ xb, const unsigned short* __restrict__ aggb,
               const unsigned short* __restrict__ Bsw, const float* __restrict__ bias2,
               float* __restrict__ pooled_pad, int M, int NT) {
    __shared__ unsigned short As[4 * 32 * 256];   // 64 KB: 4 bufs x (32 rows x 512 B)
    const int tid  = threadIdx.x;
    const int lane = tid & 63;
    const int wn2  = tid >> 6;        // wave = 64-col group 0..3
    const int lrow = lane & 15;
    const int quad = lane >> 4;
    const int bid  = blockIdx.x;
    const int GRID = gridDim.x;
    const int nt   = (NT - bid + GRID - 1) / GRID;   // tiles for this block
    if (nt <= 0) return;

    // ---- B frags (32 x uint4 = 128 VGPR) + bias, once per block (L2-hot) ----
    uint4 bb[8][4];
    #pragma unroll
    for (int kk = 0; kk < 8; ++kk)
        #pragma unroll
        for (int t = 0; t < 4; ++t)
            bb[kk][t] = *(const uint4*)&Bsw[((((long)kk * 4 + wn2) * 4 + t) * 64 + lane) * 8];
    float bv[4];
    #pragma unroll
    for (int t = 0; t < 4; ++t) bv[t] = bias2[wn2 * 64 + t * 16 + lrow];

    // staging: thread covers (row%8 = rw, LDS chunk cl), source chunk cl^rw
    const int cl = tid & 31;
    const int rw = tid >> 5;
    const int cs = cl ^ rw;
    const unsigned short* sbase = (cs < 16) ? (xb + (long)cs * 8)
                                            : (aggb + (long)(cs - 16) * 8);
    char* lbase = (char*)As + rw * 512 + cl * 16;

    auto STAGE = [&](int p) {
        const long trow = ((long)bid + (long)p * GRID) * 32;
        char* ld = lbase + (p & 3) * 16384;
        #pragma unroll
        for (int s = 0; s < 4; ++s)
            g2lds16(sbase + (trow + s * 8 + rw) * 128, ld + s * 4096);
    };

    #pragma unroll
    for (int p = 0; p < 3; ++p) if (p < nt) STAGE(p);

    float ps[4] = {0.f, 0.f, 0.f, 0.f};

    for (int p = 0; p < nt; ++p) {
        const int rem = nt - 1 - p;
        if (rem >= 2)      asm volatile("s_waitcnt vmcnt(8)" ::: "memory");
        else if (rem == 1) asm volatile("s_waitcnt vmcnt(4)" ::: "memory");
        else               asm volatile("s_waitcnt vmcnt(0)" ::: "memory");
        __builtin_amdgcn_s_barrier();
        if (p + 3 < nt) STAGE(p + 3);   // 12 wave-loads in flight during compute

        const char* Ab = (const char*)As + (p & 3) * 16384;
        f32x4 acc[2][4] = {};
        #pragma unroll
        for (int kk = 0; kk < 8; ++kk) {
            uint4 aC[2];
            #pragma unroll
            for (int i = 0; i < 2; ++i) {
                const int r = i * 16 + lrow;   // r&7 == lrow&7
                aC[i] = *(const uint4*)(Ab + r * 512 + (((kk * 4 + quad) ^ (lrow & 7)) * 16));
            }
            #pragma unroll
            for (int i = 0; i < 2; ++i)
                #pragma unroll
                for (int t = 0; t < 4; ++t)
                    acc[i][t] = __builtin_amdgcn_mfma_f32_16x16x32_bf16(
                        *(bf16x8*)&aC[i], *(bf16x8*)&bb[kk][t], acc[i][t], 0, 0, 0);
        }

        // bias + ReLU + masked row-sum, accumulated in registers across tiles
        const long trow = ((long)bid + (long)p * GRID) * 32;
        #pragma unroll
        for (int t = 0; t < 4; ++t) {
            float s = 0.f;
            #pragma unroll
            for (int i = 0; i < 2; ++i) {
                const long rbase = trow + i * 16 + quad * 4;
                #pragma unroll
                for (int r = 0; r < 4; ++r) {
                    float h = fmaxf(acc[i][t][r] + bv[t], 0.f);
                    if (rbase + r < M) s += h;
                }
            }
            ps[t] += s;
        }
    }

    // single pooled flush per block
    #pragma unroll
    for (int t = 0; t < 4; ++t) {
        ps[t] += __shfl_xor(ps[t], 16);
        ps[t] += __shfl_xor(ps[t], 32);
        if (quad == 0)
            atomicAdd(&pooled_pad[(wn2 * 64 + t * 16 + lrow) * 16], ps[t]);
    }
}

// pooled -> MLP head -> log_softmax. One block, 256 threads.
__global__ __launch_bounds__(256)
void head_kernel(const float* __restrict__ pooled_pad,
                 const float* __restrict__ W1, const float* __restrict__ b1,
                 const float* __restrict__ W2, const float* __restrict__ b2,
                 float* __restrict__ out, float invM) {
    __shared__ float pooled_s[256];
    __shared__ float z1_s[256];
    __shared__ float z2_s[10];
    const int j = threadIdx.x;

    pooled_s[j] = pooled_pad[j * 16] * invM;
    __syncthreads();

    const float4* w4 = (const float4*)(W1 + (long)j * 256);
    float sx = 0.f, sy = 0.f, sz = 0.f, sw = 0.f;
    #pragma unroll 8
    for (int k = 0; k < 64; ++k) {
        float4 w = w4[k];
        float4 p = *(const float4*)&pooled_s[k * 4];
        sx += w.x * p.x; sy += w.y * p.y; sz += w.z * p.z; sw += w.w * p.w;
    }
    z1_s[j] = fmaxf(b1[j] + sx + sy + sz + sw, 0.f);
    __syncthreads();

    if (j < 160) {
        const int c = j >> 4, q = j & 15;
        float s = 0.f;
        for (int k = q; k < 256; k += 16) s += W2[c * 256 + k] * z1_s[k];
        #pragma unroll
        for (int off = 8; off >= 1; off >>= 1) s += __shfl_down(s, off, 16);
        if (q == 0) z2_s[c] = s + b2[c];
    }
    __syncthreads();

    if (j == 0) {
        float mx = z2_s[0];
        for (int c = 1; c < 10; ++c) mx = fmaxf(mx, z2_s[c]);
        float se = 0.f;
        for (int c = 0; c < 10; ++c) se += expf(z2_s[c] - mx);
        const float ls = logf(se);
        for (int c = 0; c < 10; ++c) out[c] = z2_s[c] - mx - ls;
    }
}

extern "C" void kernel_launch(void* const* d_in, const int* in_sizes, int n_in,
                              void* d_out, int out_size, void* d_ws, size_t ws_size,
                              hipStream_t stream) {
    const float* x    = (const float*)d_in[0];
    const void*  ei   = d_in[1];
    const float* Wl   = (const float*)d_in[2];
    const float* Wr   = (const float*)d_in[3];
    const float* bias = (const float*)d_in[4];
    const float* W1   = (const float*)d_in[5];
    const float* b1   = (const float*)d_in[6];
    const float* W2   = (const float*)d_in[7];
    const float* b2   = (const float*)d_in[8];
    float* out = (float*)d_out;

    const int M = in_sizes[0] / D_IN;        // 100000 nodes
    const int E = in_sizes[1] / 2;           // 1.6M edges
    const int L = in_sizes[4] / D_HID;       // 3 layers
    const int NMB = (M + 127) / 128;         // 128-row pad granules
    const long Mpad = (long)NMB * 128;       // row-padded region size (GEMM OOB-safe)
    const int NCB = (M + CSIZE - 1) / CSIZE; // buckets (782)
    const int NB1 = (E + EPB - 1) / EPB;     // binning blocks (391)
    const int NT  = (M + 31) / 32;           // gemm 32-row tiles (3125)
    const int NG  = (NT < 512) ? NT : 512;   // resident grid: 2 blocks/CU

    // Only the LAST layer matters (h is overwritten each loop iteration).
    const float* Wl2   = Wl + (long)(L - 1) * D_HID * D_IN;
    const float* Wr2   = Wr + (long)(L - 1) * D_HID * D_IN;
    const float* bias2 = bias + (long)(L - 1) * D_HID;

    // workspace: xb[Mpad*128]bf16 | aggb[Mpad*128]bf16 | x8[Mpad*128]u8 | Bsw[256*256]bf16 |
    //            pooled_pad[256*16]f | gcur[NCB*16]i | segc[NCB*CCAP]u
    //            (pad rows of xb/aggb are garbage; GEMM masks rows >= M)
    unsigned short* xb   = (unsigned short*)d_ws;
    unsigned short* aggb = xb + Mpad * D_IN;
    unsigned char*  x8   = (unsigned char*)(aggb + Mpad * D_IN);
    unsigned short* Bsw  = (unsigned short*)(x8 + Mpad * D_IN);
    float* pooled_pad    = (float*)(Bsw + 256 * 256);
    int*      gcur       = (int*)(pooled_pad + 256 * 16);
    unsigned* segc       = (unsigned*)(gcur + (long)NCB * 16);

    const long n4 = (long)M * 32;            // float4 chunks of x
    const int NXB2 = (int)((n4 + 4095) / 4096);

    // zero pooled_pad + gcur in one contiguous memset (graph-capturable)
    hipMemsetAsync(pooled_pad, 0, 256 * 16 * 4 + (size_t)NCB * 16 * 4, stream);

    prep_bin<<<NB1 + 16 + NXB2, 512, 0, stream>>>(x, xb, x8, Wr2, Wl2, Bsw,
                                                  ei, gcur, segc, n4, NB1, E, NCB);
    refine_gather<<<NCB, 512, 0, stream>>>(gcur, segc, x8, aggb, M);

    gemm_pool<<<NG, 256, 0, stream>>>(xb, aggb, Bsw, bias2, pooled_pad, M, NT);

    head_kernel<<<1, 256, 0, stream>>>(pooled_pad, W1, b1, W2, b2, out, 1.0f / (float)M);
}

// Round 12
// 201.104 us; speedup vs baseline: 1.0263x; 1.0263x over previous
//
#include <hip/hip_runtime.h>
#include <hip/hip_bf16.h>

#define D_IN  128
#define D_HID 256
#define CBITS 8
#define CSIZE 256          // nodes per bucket (one refine_gather block)
#define EPB   4096         // edges per coarse_bin block
#define CCAP  8192         // entry capacity per bucket (mean ~4092 + 64 sigma)

typedef __bf16 bf16x8 __attribute__((ext_vector_type(8)));
typedef float  f32x4  __attribute__((ext_vector_type(4)));
typedef float  f32x2  __attribute__((ext_vector_type(2)));

__device__ __forceinline__ unsigned short f2bf(float f) {
    unsigned u = __float_as_uint(f);
    u += 0x7FFFu + ((u >> 16) & 1u);   // RNE
    return (unsigned short)(u >> 16);
}
__device__ __forceinline__ uint2 pack4(float4 v) {
    unsigned lo = (unsigned)f2bf(v.x) | ((unsigned)f2bf(v.y) << 16);
    unsigned hi = (unsigned)f2bf(v.z) | ((unsigned)f2bf(v.w) << 16);
    return make_uint2(lo, hi);
}
// pack 4 floats -> 4 fp8 e4m3 bytes (HW cvt)
__device__ __forceinline__ unsigned packfp8(float4 v) {
    int u = __builtin_amdgcn_cvt_pk_fp8_f32(v.x, v.y, 0, false);
    u = __builtin_amdgcn_cvt_pk_fp8_f32(v.z, v.w, u, true);
    return (unsigned)u;
}
// async 16B global -> LDS (vmcnt)
__device__ __forceinline__ void g2lds16(const void* g, void* l) {
    __builtin_amdgcn_global_load_lds(
        (const __attribute__((address_space(1))) unsigned int*)g,
        (__attribute__((address_space(3))) unsigned int*)l, 16, 0, 0);
}
// accumulate 16 fp8 channels (one uint4) into 8 packed f32x2 accumulators
__device__ __forceinline__ void acc16(f32x2* a, uint4 v) {
    a[0] += __builtin_amdgcn_cvt_pk_f32_fp8(v.x, false);
    a[1] += __builtin_amdgcn_cvt_pk_f32_fp8(v.x, true);
    a[2] += __builtin_amdgcn_cvt_pk_f32_fp8(v.y, false);
    a[3] += __builtin_amdgcn_cvt_pk_f32_fp8(v.y, true);
    a[4] += __builtin_amdgcn_cvt_pk_f32_fp8(v.z, false);
    a[5] += __builtin_amdgcn_cvt_pk_f32_fp8(v.z, true);
    a[6] += __builtin_amdgcn_cvt_pk_f32_fp8(v.w, false);
    a[7] += __builtin_amdgcn_cvt_pk_f32_fp8(v.w, true);
}

// FUSED prep + coarse_bin. Binning blocks FIRST ([0,NB1)); converts fill the
// rest (round-10 64B/thread layout -- measured best; round-11 wave-contiguous
// variant regressed). CBITS=8: 391 buckets -> mean segc run per (block,bucket)
// doubles to 10.5 entries (42 B), halving partial-line write amplification
// (round 11 counters: WRITE 59.4 MB vs 44.8 logical). Wave-level shfl scan
// over 512 counters (1/lane, 8 waves).
__global__ __launch_bounds__(512)
void prep_bin(const float* __restrict__ x, unsigned short* __restrict__ xb,
              unsigned char* __restrict__ x8,
              const float* __restrict__ Wr2, const float* __restrict__ Wl2,
              unsigned short* __restrict__ Bsw,
              const void* __restrict__ ei, int* __restrict__ gcur,
              unsigned* __restrict__ segc,
              long n16, int NB1, int E, int NCB) {
    __shared__ unsigned sorted[EPB];          // 16 KB
    __shared__ unsigned short bkt[EPB];       // 8 KB
    __shared__ int cnt[512], scn[512], cur[512], gbase[512];  // 8 KB
    __shared__ int wtot[8], woff[8];
    __shared__ int s_is64;
    const int bid = blockIdx.x;
    const int tid = threadIdx.x;

    if (bid >= NB1 + 16) {
        // ---- x -> bf16 (xb) + fp8 (x8), one 16-float chunk per thread ----
        const long t = (long)(bid - NB1 - 16) * 512 + tid;
        if (t >= n16) return;
        const float4* x4 = (const float4*)x;
        float4 v0 = x4[t * 4], v1 = x4[t * 4 + 1], v2 = x4[t * 4 + 2], v3 = x4[t * 4 + 3];
        uint2 p0 = pack4(v0), p1 = pack4(v1), p2 = pack4(v2), p3 = pack4(v3);
        ((uint4*)xb)[t * 2]     = make_uint4(p0.x, p0.y, p1.x, p1.y);
        ((uint4*)xb)[t * 2 + 1] = make_uint4(p2.x, p2.y, p3.x, p3.y);
        ((uint4*)x8)[t] = make_uint4(packfp8(v0), packfp8(v1), packfp8(v2), packfp8(v3));
        return;
    }
    if (bid >= NB1) {
        // ---- B pack into MFMA-fragment order ----
        // Bsw[(((kk*4+wn2)*4+t)*64+lane)*8+e] = B[wn2*64+t*16+(lane&15)][kk*32+(lane>>4)*8+e]
        const int t_idx = (bid - NB1) * 512 + tid;
        const int lane = t_idx & 63;
        const int rest = t_idx >> 6;
        const int tt   = rest & 3;
        const int wn2  = (rest >> 2) & 3;
        const int kk   = rest >> 4;
        const int j = wn2 * 64 + tt * 16 + (lane & 15);
        const int k = kk * 32 + (lane >> 4) * 8;
        const float* src = (k < 128) ? &Wr2[j * 128 + k] : &Wl2[j * 128 + (k - 128)];
        float4 v0 = *(const float4*)src;
        float4 v1 = *(const float4*)(src + 4);
        uint2 p0 = pack4(v0), p1 = pack4(v1);
        *(uint4*)&Bsw[(long)t_idx * 8] = make_uint4(p0.x, p0.y, p1.x, p1.y);
        return;
    }

    // ---- coarse_bin: block-local counting sort (registers + LDS) ----
    const long e0 = (long)bid * EPB;
    const int ecnt = (int)min((long)EPB, (long)E - e0);

    if (tid < 64) {
        const int v = ((const int*)ei)[2 * tid + 1];
        const unsigned long long b = __ballot(v != 0);
        if (tid == 0) s_is64 = (b == 0ull);
    }
    if (tid < 512) cnt[tid] = 0;
    __syncthreads();
    const int is64 = s_is64;

    // load edges into registers + histogram
    int sv[8], tv[8];
    #pragma unroll
    for (int k = 0; k < 8; ++k) {
        const int j = tid + k * 512;
        if (j < ecnt) {
            if (is64) {
                sv[k] = (int)((const long long*)ei)[e0 + j];
                tv[k] = (int)((const long long*)ei)[E + e0 + j];
            } else {
                sv[k] = ((const int*)ei)[e0 + j];
                tv[k] = ((const int*)ei)[E + e0 + j];
            }
            atomicAdd(&cnt[tv[k] >> CBITS], 1);
        }
    }
    __syncthreads();   // histogram complete

    // global segment base per bucket (independent of scan -> overlaps it)
    if (tid < NCB)
        gbase[tid] = cnt[tid] ? atomicAdd(&gcur[tid * 16], cnt[tid]) : 0;

    // wave-level scan: wave wv owns counters [wv*64, wv*64+64), 1 per lane
    {
        const int wv = tid >> 6, ln = tid & 63;
        const int i0 = wv * 64 + ln;
        const int c0 = cnt[i0];
        int sc = c0;
        #pragma unroll
        for (int off = 1; off < 64; off <<= 1) {
            const int v = __shfl_up(sc, off);
            if (ln >= off) sc += v;
        }
        if (ln == 63) wtot[wv] = sc;
        __syncthreads();   // wtot ready (also covers gbase)
        if (tid == 0) {
            int s = 0;
            #pragma unroll
            for (int w = 0; w < 8; ++w) { woff[w] = s; s += wtot[w]; }
        }
        __syncthreads();
        const int ebase = woff[wv] + sc - c0;   // exclusive prefix
        cur[i0] = ebase;                        // scatter cursor (exclusive)
        scn[i0] = ebase + c0;                   // inclusive (run start = scn-cnt)
    }
    __syncthreads();

    // scatter into LDS sorted order
    #pragma unroll
    for (int k = 0; k < 8; ++k) {
        const int j = tid + k * 512;
        if (j < ecnt) {
            const int c = tv[k] >> CBITS;
            const int r = atomicAdd(&cur[c], 1);
            sorted[r] = ((unsigned)sv[k] << CBITS) | (unsigned)(tv[k] & (CSIZE - 1));
            bkt[r] = (unsigned short)c;
        }
    }
    __syncthreads();

    // streamed, run-coalesced write-out (runs now ~10.5 entries = 42 B)
    for (int i = tid; i < ecnt; i += 512) {
        const int c = bkt[i];
        const int pos = gbase[c] + (i - (scn[c] - cnt[c]));
        if (pos < CCAP) segc[(long)c * CCAP + pos] = sorted[i];
    }
}

// Stage 2+3 FUSED: per 256-node bucket (512 thr, 8 waves): histogram + wave-0
// shfl scan (4 counters/lane) + scatter build the node-ordered edge list IN
// LDS (order[8192], 32 KB), then the gather consumes it in place. Wave = 8
// node-slots x 8 lanes; each 8-lane group owns one node's full 128-B fp8 row
// (uint4/lane = 16 B); 4-edge unroll; dual accumulator sets. No cross-lane
// reduction. order[] entry: byte offset into x8 = (e >> CBITS) << 7.
__global__ __launch_bounds__(512)
void refine_gather(const int* __restrict__ gcur, const unsigned* __restrict__ segc,
                   const unsigned char* __restrict__ x8,
                   unsigned short* __restrict__ aggb, int M) {
    __shared__ unsigned order[CCAP];            // 32 KB (src byte offsets)
    __shared__ int degh[CSIZE], scn[CSIZE], cur[CSIZE];
    const int tid = threadIdx.x;
    const int cb = blockIdx.x;
    const int nbase = cb << CBITS;
    const int nn = min(CSIZE, M - nbase);
    const int len = min(gcur[cb * 16], CCAP);
    const unsigned* sp = segc + (long)cb * CCAP;

    if (tid < CSIZE) degh[tid] = 0;
    __syncthreads();
    for (int i = tid; i < len; i += 512) {
        const unsigned e = sp[i];
        atomicAdd(&degh[e & (CSIZE - 1)], 1);
    }
    __syncthreads();   // histogram complete

    // wave 0 shfl-scans the 256 counters (4 per lane)
    if (tid < 64) {
        const int i0 = tid * 4;
        const int c0 = degh[i0], c1 = degh[i0 + 1], c2 = degh[i0 + 2], c3 = degh[i0 + 3];
        const int quad = c0 + c1 + c2 + c3;
        int sc = quad;
        #pragma unroll
        for (int off = 1; off < 64; off <<= 1) {
            const int v = __shfl_up(sc, off);
            if (tid >= off) sc += v;
        }
        const int eb = sc - quad;      // exclusive prefix of quad
        cur[i0]     = eb;
        cur[i0 + 1] = eb + c0;
        cur[i0 + 2] = eb + c0 + c1;
        cur[i0 + 3] = eb + c0 + c1 + c2;
        scn[i0]     = eb + c0;         // inclusive
        scn[i0 + 1] = eb + c0 + c1;
        scn[i0 + 2] = eb + c0 + c1 + c2;
        scn[i0 + 3] = eb + quad;
    }
    __syncthreads();

    for (int i = tid; i < len; i += 512) {
        const unsigned e = sp[i];
        const int r = atomicAdd(&cur[e & (CSIZE - 1)], 1);
        order[r] = (e >> CBITS) << 7;   // src * 128 = byte offset into x8
    }
    __syncthreads();

    // ---- gather phase ----
    const int lane = tid & 63;
    const int wave = tid >> 6;       // 0..7
    const int ns   = lane >> 3;      // node slot 0..7
    const int c4   = lane & 7;       // uint4 column: channels c4*16 .. c4*16+15
    const unsigned chb = (unsigned)c4 * 16;

    for (int base = wave * 8; base < nn; base += 64) {
        const int nl = base + ns;
        int deg = 0, beg = 0;
        if (nl < nn) { deg = degh[nl]; beg = scn[nl] - deg; }
        f32x2 a[8] = {}, b[8] = {};
        int i = 0;
        for (; i + 4 <= deg; i += 4) {
            const unsigned o0 = order[beg + i];
            const unsigned o1 = order[beg + i + 1];
            const unsigned o2 = order[beg + i + 2];
            const unsigned o3 = order[beg + i + 3];
            uint4 v0 = *(const uint4*)(x8 + (o0 + chb));
            uint4 v1 = *(const uint4*)(x8 + (o1 + chb));
            uint4 v2 = *(const uint4*)(x8 + (o2 + chb));
            uint4 v3 = *(const uint4*)(x8 + (o3 + chb));
            acc16(a, v0); acc16(b, v1); acc16(a, v2); acc16(b, v3);
        }
        if (i < deg) {
            uint4 v = *(const uint4*)(x8 + (order[beg + i] + chb));
            acc16(a, v); ++i;
        }
        if (i < deg) {
            uint4 v = *(const uint4*)(x8 + (order[beg + i] + chb));
            acc16(b, v); ++i;
        }
        if (i < deg) {
            uint4 v = *(const uint4*)(x8 + (order[beg + i] + chb));
            acc16(a, v); ++i;
        }
        if (nl < nn) {
            const float rdiv = 1.0f / fmaxf((float)deg, 1.0f);
            unsigned w[8];
            #pragma unroll
            for (int j = 0; j < 8; ++j) {
                const f32x2 s = a[j] + b[j];
                w[j] = (unsigned)f2bf(s.x * rdiv) | ((unsigned)f2bf(s.y * rdiv) << 16);
            }
            unsigned short* dst = aggb + (long)(nbase + nl) * 128 + c4 * 16;
            *(uint4*)dst       = make_uint4(w[0], w[1], w[2], w[3]);
            *(uint4*)(dst + 8) = make_uint4(w[4], w[5], w[6], w[7]);
        }
    }
}

// GEMM v4: T3+T4 pipelined M-loop, 512 resident blocks (2/CU), 4-deep LDS ring
// (4 x 16 KB = 64 KB), counted s_waitcnt vmcnt (never 0 in steady state), ONE
// raw s_barrier per tile, B + bias hoisted to registers once per block, pool
// accumulated in registers with a single atomic flush. NO in-kernel grid sync
// (round 7: per-block __threadfence + done-counter cost ~25us).
__global__ __launch_bounds__(256, 2)
void gemm_pool(const unsigned short* __restrict__ xb, const unsigned short* __restrict__ aggb,
               const unsigned short* __restrict__ Bsw, const float* __restrict__ bias2,
               float* __restrict__ pooled_pad, int M, int NT) {
    __shared__ unsigned short As[4 * 32 * 256];   // 64 KB: 4 bufs x (32 rows x 512 B)
    const int tid  = threadIdx.x;
    const int lane = tid & 63;
    const int wn2  = tid >> 6;        // wave = 64-col group 0..3
    const int lrow = lane & 15;
    const int quad = lane >> 4;
    const int bid  = blockIdx.x;
    const int GRID = gridDim.x;
    const int nt   = (NT - bid + GRID - 1) / GRID;   // tiles for this block
    if (nt <= 0) return;

    // ---- B frags (32 x uint4 = 128 VGPR) + bias, once per block (L2-hot) ----
    uint4 bb[8][4];
    #pragma unroll
    for (int kk = 0; kk < 8; ++kk)
        #pragma unroll
        for (int t = 0; t < 4; ++t)
            bb[kk][t] = *(const uint4*)&Bsw[((((long)kk * 4 + wn2) * 4 + t) * 64 + lane) * 8];
    float bv[4];
    #pragma unroll
    for (int t = 0; t < 4; ++t) bv[t] = bias2[wn2 * 64 + t * 16 + lrow];

    // staging: thread covers (row%8 = rw, LDS chunk cl), source chunk cl^rw
    const int cl = tid & 31;
    const int rw = tid >> 5;
    const int cs = cl ^ rw;
    const unsigned short* sbase = (cs < 16) ? (xb + (long)cs * 8)
                                            : (aggb + (long)(cs - 16) * 8);
    char* lbase = (char*)As + rw * 512 + cl * 16;

    auto STAGE = [&](int p) {
        const long trow = ((long)bid + (long)p * GRID) * 32;
        char* ld = lbase + (p & 3) * 16384;
        #pragma unroll
        for (int s = 0; s < 4; ++s)
            g2lds16(sbase + (trow + s * 8 + rw) * 128, ld + s * 4096);
    };

    #pragma unroll
    for (int p = 0; p < 3; ++p) if (p < nt) STAGE(p);

    float ps[4] = {0.f, 0.f, 0.f, 0.f};

    for (int p = 0; p < nt; ++p) {
        const int rem = nt - 1 - p;
        if (rem >= 2)      asm volatile("s_waitcnt vmcnt(8)" ::: "memory");
        else if (rem == 1) asm volatile("s_waitcnt vmcnt(4)" ::: "memory");
        else               asm volatile("s_waitcnt vmcnt(0)" ::: "memory");
        __builtin_amdgcn_s_barrier();
        if (p + 3 < nt) STAGE(p + 3);   // 12 wave-loads in flight during compute

        const char* Ab = (const char*)As + (p & 3) * 16384;
        f32x4 acc[2][4] = {};
        #pragma unroll
        for (int kk = 0; kk < 8; ++kk) {
            uint4 aC[2];
            #pragma unroll
            for (int i = 0; i < 2; ++i) {
                const int r = i * 16 + lrow;   // r&7 == lrow&7
                aC[i] = *(const uint4*)(Ab + r * 512 + (((kk * 4 + quad) ^ (lrow & 7)) * 16));
            }
            #pragma unroll
            for (int i = 0; i < 2; ++i)
                #pragma unroll
                for (int t = 0; t < 4; ++t)
                    acc[i][t] = __builtin_amdgcn_mfma_f32_16x16x32_bf16(
                        *(bf16x8*)&aC[i], *(bf16x8*)&bb[kk][t], acc[i][t], 0, 0, 0);
        }

        // bias + ReLU + masked row-sum, accumulated in registers across tiles
        const long trow = ((long)bid + (long)p * GRID) * 32;
        #pragma unroll
        for (int t = 0; t < 4; ++t) {
            float s = 0.f;
            #pragma unroll
            for (int i = 0; i < 2; ++i) {
                const long rbase = trow + i * 16 + quad * 4;
                #pragma unroll
                for (int r = 0; r < 4; ++r) {
                    float h = fmaxf(acc[i][t][r] + bv[t], 0.f);
                    if (rbase + r < M) s += h;
                }
            }
            ps[t] += s;
        }
    }

    // single pooled flush per block
    #pragma unroll
    for (int t = 0; t < 4; ++t) {
        ps[t] += __shfl_xor(ps[t], 16);
        ps[t] += __shfl_xor(ps[t], 32);
        if (quad == 0)
            atomicAdd(&pooled_pad[(wn2 * 64 + t * 16 + lrow) * 16], ps[t]);
    }
}

// pooled -> MLP head -> log_softmax. One block, 256 threads.
__global__ __launch_bounds__(256)
void head_kernel(const float* __restrict__ pooled_pad,
                 const float* __restrict__ W1, const float* __restrict__ b1,
                 const float* __restrict__ W2, const float* __restrict__ b2,
                 float* __restrict__ out, float invM) {
    __shared__ float pooled_s[256];
    __shared__ float z1_s[256];
    __shared__ float z2_s[10];
    const int j = threadIdx.x;

    pooled_s[j] = pooled_pad[j * 16] * invM;
    __syncthreads();

    const float4* w4 = (const float4*)(W1 + (long)j * 256);
    float sx = 0.f, sy = 0.f, sz = 0.f, sw = 0.f;
    #pragma unroll 8
    for (int k = 0; k < 64; ++k) {
        float4 w = w4[k];
        float4 p = *(const float4*)&pooled_s[k * 4];
        sx += w.x * p.x; sy += w.y * p.y; sz += w.z * p.z; sw += w.w * p.w;
    }
    z1_s[j] = fmaxf(b1[j] + sx + sy + sz + sw, 0.f);
    __syncthreads();

    if (j < 160) {
        const int c = j >> 4, q = j & 15;
        float s = 0.f;
        for (int k = q; k < 256; k += 16) s += W2[c * 256 + k] * z1_s[k];
        #pragma unroll
        for (int off = 8; off >= 1; off >>= 1) s += __shfl_down(s, off, 16);
        if (q == 0) z2_s[c] = s + b2[c];
    }
    __syncthreads();

    if (j == 0) {
        float mx = z2_s[0];
        for (int c = 1; c < 10; ++c) mx = fmaxf(mx, z2_s[c]);
        float se = 0.f;
        for (int c = 0; c < 10; ++c) se += expf(z2_s[c] - mx);
        const float ls = logf(se);
        for (int c = 0; c < 10; ++c) out[c] = z2_s[c] - mx - ls;
    }
}

extern "C" void kernel_launch(void* const* d_in, const int* in_sizes, int n_in,
                              void* d_out, int out_size, void* d_ws, size_t ws_size,
                              hipStream_t stream) {
    const float* x    = (const float*)d_in[0];
    const void*  ei   = d_in[1];
    const float* Wl   = (const float*)d_in[2];
    const float* Wr   = (const float*)d_in[3];
    const float* bias = (const float*)d_in[4];
    const float* W1   = (const float*)d_in[5];
    const float* b1   = (const float*)d_in[6];
    const float* W2   = (const float*)d_in[7];
    const float* b2   = (const float*)d_in[8];
    float* out = (float*)d_out;

    const int M = in_sizes[0] / D_IN;        // 100000 nodes
    const int E = in_sizes[1] / 2;           // 1.6M edges
    const int L = in_sizes[4] / D_HID;       // 3 layers
    const int NMB = (M + 127) / 128;         // 128-row pad granules
    const long Mpad = (long)NMB * 128;       // row-padded region size (GEMM OOB-safe)
    const int NCB = (M + CSIZE - 1) / CSIZE; // buckets (391)
    const int NB1 = (E + EPB - 1) / EPB;     // binning blocks (391)
    const int NT  = (M + 31) / 32;           // gemm 32-row tiles (3125)
    const int NG  = (NT < 512) ? NT : 512;   // resident grid: 2 blocks/CU

    // Only the LAST layer matters (h is overwritten each loop iteration).
    const float* Wl2   = Wl + (long)(L - 1) * D_HID * D_IN;
    const float* Wr2   = Wr + (long)(L - 1) * D_HID * D_IN;
    const float* bias2 = bias + (long)(L - 1) * D_HID;

    // workspace: xb[Mpad*128]bf16 | aggb[Mpad*128]bf16 | x8[Mpad*128]u8 | Bsw[256*256]bf16 |
    //            pooled_pad[256*16]f | gcur[NCB*16]i | segc[NCB*CCAP]u
    //            (pad rows of xb/aggb are garbage; GEMM masks rows >= M)
    unsigned short* xb   = (unsigned short*)d_ws;
    unsigned short* aggb = xb + Mpad * D_IN;
    unsigned char*  x8   = (unsigned char*)(aggb + Mpad * D_IN);
    unsigned short* Bsw  = (unsigned short*)(x8 + Mpad * D_IN);
    float* pooled_pad    = (float*)(Bsw + 256 * 256);
    int*      gcur       = (int*)(pooled_pad + 256 * 16);
    unsigned* segc       = (unsigned*)(gcur + (long)NCB * 16);

    const long n16 = (long)M * 8;            // 16-float chunks of x
    const int NXB2 = (int)((n16 + 511) / 512);

    // zero pooled_pad + gcur in one contiguous memset (graph-capturable)
    hipMemsetAsync(pooled_pad, 0, 256 * 16 * 4 + (size_t)NCB * 16 * 4, stream);

    prep_bin<<<NB1 + 16 + NXB2, 512, 0, stream>>>(x, xb, x8, Wr2, Wl2, Bsw,
                                                  ei, gcur, segc, n16, NB1, E, NCB);
    refine_gather<<<NCB, 512, 0, stream>>>(gcur, segc, x8, aggb, M);

    gemm_pool<<<NG, 256, 0, stream>>>(xb, aggb, Bsw, bias2, pooled_pad, M, NT);

    head_kernel<<<1, 256, 0, stream>>>(pooled_pad, W1, b1, W2, b2, out, 1.0f / (float)M);
}

// Round 13
// 192.803 us; speedup vs baseline: 1.0704x; 1.0431x over previous
//
#include <hip/hip_runtime.h>
#include <hip/hip_bf16.h>

#define D_IN  128
#define D_HID 256
#define CBITS 8
#define CSIZE 256          // nodes per bucket (one refine_gather block)
#define EPB   4096         // edges per coarse_bin block
#define CCAP  8192         // entry capacity per bucket (mean ~4092 + 64 sigma)

typedef __bf16 bf16x8 __attribute__((ext_vector_type(8)));
typedef float  f32x4  __attribute__((ext_vector_type(4)));
typedef float  f32x2  __attribute__((ext_vector_type(2)));

__device__ __forceinline__ unsigned short f2bf(float f) {
    unsigned u = __float_as_uint(f);
    u += 0x7FFFu + ((u >> 16) & 1u);   // RNE
    return (unsigned short)(u >> 16);
}
__device__ __forceinline__ uint2 pack4(float4 v) {
    unsigned lo = (unsigned)f2bf(v.x) | ((unsigned)f2bf(v.y) << 16);
    unsigned hi = (unsigned)f2bf(v.z) | ((unsigned)f2bf(v.w) << 16);
    return make_uint2(lo, hi);
}
// pack 4 floats -> 4 fp8 e4m3 bytes (HW cvt)
__device__ __forceinline__ unsigned packfp8(float4 v) {
    int u = __builtin_amdgcn_cvt_pk_fp8_f32(v.x, v.y, 0, false);
    u = __builtin_amdgcn_cvt_pk_fp8_f32(v.z, v.w, u, true);
    return (unsigned)u;
}
// async 16B global -> LDS (vmcnt)
__device__ __forceinline__ void g2lds16(const void* g, void* l) {
    __builtin_amdgcn_global_load_lds(
        (const __attribute__((address_space(1))) unsigned int*)g,
        (__attribute__((address_space(3))) unsigned int*)l, 16, 0, 0);
}
// accumulate 16 fp8 channels (one uint4) into 8 packed f32x2 accumulators
__device__ __forceinline__ void acc16(f32x2* a, uint4 v) {
    a[0] += __builtin_amdgcn_cvt_pk_f32_fp8(v.x, false);
    a[1] += __builtin_amdgcn_cvt_pk_f32_fp8(v.x, true);
    a[2] += __builtin_amdgcn_cvt_pk_f32_fp8(v.y, false);
    a[3] += __builtin_amdgcn_cvt_pk_f32_fp8(v.y, true);
    a[4] += __builtin_amdgcn_cvt_pk_f32_fp8(v.z, false);
    a[5] += __builtin_amdgcn_cvt_pk_f32_fp8(v.z, true);
    a[6] += __builtin_amdgcn_cvt_pk_f32_fp8(v.w, false);
    a[7] += __builtin_amdgcn_cvt_pk_f32_fp8(v.w, true);
}

// FUSED prep + coarse_bin. Binning blocks FIRST ([0,NB1)); converts fill the
// rest (64B/thread layout -- measured best). CBITS=8: 391 buckets -> mean segc
// run per (block,bucket) = 10.5 entries (42 B). Wave-level shfl scan.
__global__ __launch_bounds__(512)
void prep_bin(const float* __restrict__ x, unsigned short* __restrict__ xb,
              unsigned char* __restrict__ x8,
              const float* __restrict__ Wr2, const float* __restrict__ Wl2,
              unsigned short* __restrict__ Bsw,
              const void* __restrict__ ei, int* __restrict__ gcur,
              unsigned* __restrict__ segc,
              long n16, int NB1, int E, int NCB) {
    __shared__ unsigned sorted[EPB];          // 16 KB
    __shared__ unsigned short bkt[EPB];       // 8 KB
    __shared__ int cnt[512], scn[512], cur[512], gbase[512];  // 8 KB
    __shared__ int wtot[8], woff[8];
    __shared__ int s_is64;
    const int bid = blockIdx.x;
    const int tid = threadIdx.x;

    if (bid >= NB1 + 16) {
        // ---- x -> bf16 (xb) + fp8 (x8), one 16-float chunk per thread ----
        const long t = (long)(bid - NB1 - 16) * 512 + tid;
        if (t >= n16) return;
        const float4* x4 = (const float4*)x;
        float4 v0 = x4[t * 4], v1 = x4[t * 4 + 1], v2 = x4[t * 4 + 2], v3 = x4[t * 4 + 3];
        uint2 p0 = pack4(v0), p1 = pack4(v1), p2 = pack4(v2), p3 = pack4(v3);
        ((uint4*)xb)[t * 2]     = make_uint4(p0.x, p0.y, p1.x, p1.y);
        ((uint4*)xb)[t * 2 + 1] = make_uint4(p2.x, p2.y, p3.x, p3.y);
        ((uint4*)x8)[t] = make_uint4(packfp8(v0), packfp8(v1), packfp8(v2), packfp8(v3));
        return;
    }
    if (bid >= NB1) {
        // ---- B pack into MFMA-fragment order ----
        // Bsw[(((kk*4+wn2)*4+t)*64+lane)*8+e] = B[wn2*64+t*16+(lane&15)][kk*32+(lane>>4)*8+e]
        const int t_idx = (bid - NB1) * 512 + tid;
        const int lane = t_idx & 63;
        const int rest = t_idx >> 6;
        const int tt   = rest & 3;
        const int wn2  = (rest >> 2) & 3;
        const int kk   = rest >> 4;
        const int j = wn2 * 64 + tt * 16 + (lane & 15);
        const int k = kk * 32 + (lane >> 4) * 8;
        const float* src = (k < 128) ? &Wr2[j * 128 + k] : &Wl2[j * 128 + (k - 128)];
        float4 v0 = *(const float4*)src;
        float4 v1 = *(const float4*)(src + 4);
        uint2 p0 = pack4(v0), p1 = pack4(v1);
        *(uint4*)&Bsw[(long)t_idx * 8] = make_uint4(p0.x, p0.y, p1.x, p1.y);
        return;
    }

    // ---- coarse_bin: block-local counting sort (registers + LDS) ----
    const long e0 = (long)bid * EPB;
    const int ecnt = (int)min((long)EPB, (long)E - e0);

    if (tid < 64) {
        const int v = ((const int*)ei)[2 * tid + 1];
        const unsigned long long b = __ballot(v != 0);
        if (tid == 0) s_is64 = (b == 0ull);
    }
    if (tid < 512) cnt[tid] = 0;
    __syncthreads();
    const int is64 = s_is64;

    // load edges into registers + histogram
    int sv[8], tv[8];
    #pragma unroll
    for (int k = 0; k < 8; ++k) {
        const int j = tid + k * 512;
        if (j < ecnt) {
            if (is64) {
                sv[k] = (int)((const long long*)ei)[e0 + j];
                tv[k] = (int)((const long long*)ei)[E + e0 + j];
            } else {
                sv[k] = ((const int*)ei)[e0 + j];
                tv[k] = ((const int*)ei)[E + e0 + j];
            }
            atomicAdd(&cnt[tv[k] >> CBITS], 1);
        }
    }
    __syncthreads();   // histogram complete

    // global segment base per bucket (independent of scan -> overlaps it)
    if (tid < NCB)
        gbase[tid] = cnt[tid] ? atomicAdd(&gcur[tid * 16], cnt[tid]) : 0;

    // wave-level scan: wave wv owns counters [wv*64, wv*64+64), 1 per lane
    {
        const int wv = tid >> 6, ln = tid & 63;
        const int i0 = wv * 64 + ln;
        const int c0 = cnt[i0];
        int sc = c0;
        #pragma unroll
        for (int off = 1; off < 64; off <<= 1) {
            const int v = __shfl_up(sc, off);
            if (ln >= off) sc += v;
        }
        if (ln == 63) wtot[wv] = sc;
        __syncthreads();   // wtot ready (also covers gbase)
        if (tid == 0) {
            int s = 0;
            #pragma unroll
            for (int w = 0; w < 8; ++w) { woff[w] = s; s += wtot[w]; }
        }
        __syncthreads();
        const int ebase = woff[wv] + sc - c0;   // exclusive prefix
        cur[i0] = ebase;                        // scatter cursor (exclusive)
        scn[i0] = ebase + c0;                   // inclusive (run start = scn-cnt)
    }
    __syncthreads();

    // scatter into LDS sorted order
    #pragma unroll
    for (int k = 0; k < 8; ++k) {
        const int j = tid + k * 512;
        if (j < ecnt) {
            const int c = tv[k] >> CBITS;
            const int r = atomicAdd(&cur[c], 1);
            sorted[r] = ((unsigned)sv[k] << CBITS) | (unsigned)(tv[k] & (CSIZE - 1));
            bkt[r] = (unsigned short)c;
        }
    }
    __syncthreads();

    // streamed, run-coalesced write-out (runs ~10.5 entries = 42 B)
    for (int i = tid; i < ecnt; i += 512) {
        const int c = bkt[i];
        const int pos = gbase[c] + (i - (scn[c] - cnt[c]));
        if (pos < CCAP) segc[(long)c * CCAP + pos] = sorted[i];
    }
}

// Stage 2+3 FUSED, now 1024 threads/block (16 waves): round 12 showed 391
// 8-wave blocks = 1.53 blocks/CU = ~12 waves/CU -> occupancy 23.5%, latency-
// bound on random 128-B x8 row reads (x8 12.8 MB > per-XCD L2). Doubling
// waves/block doubles the outstanding-load pool per CU. Sort phase strides by
// 1024; gather = 16 waves x 8 node-slots = 128 slots over 256 nodes (2
// passes). Same 35 KB LDS; thread count is the residency limit (2 blocks/CU).
__global__ __launch_bounds__(1024)
void refine_gather(const int* __restrict__ gcur, const unsigned* __restrict__ segc,
                   const unsigned char* __restrict__ x8,
                   unsigned short* __restrict__ aggb, int M) {
    __shared__ unsigned order[CCAP];            // 32 KB (src byte offsets)
    __shared__ int degh[CSIZE], scn[CSIZE], cur[CSIZE];
    const int tid = threadIdx.x;
    const int cb = blockIdx.x;
    const int nbase = cb << CBITS;
    const int nn = min(CSIZE, M - nbase);
    const int len = min(gcur[cb * 16], CCAP);
    const unsigned* sp = segc + (long)cb * CCAP;

    if (tid < CSIZE) degh[tid] = 0;
    __syncthreads();
    for (int i = tid; i < len; i += 1024) {
        const unsigned e = sp[i];
        atomicAdd(&degh[e & (CSIZE - 1)], 1);
    }
    __syncthreads();   // histogram complete

    // wave 0 shfl-scans the 256 counters (4 per lane)
    if (tid < 64) {
        const int i0 = tid * 4;
        const int c0 = degh[i0], c1 = degh[i0 + 1], c2 = degh[i0 + 2], c3 = degh[i0 + 3];
        const int quad = c0 + c1 + c2 + c3;
        int sc = quad;
        #pragma unroll
        for (int off = 1; off < 64; off <<= 1) {
            const int v = __shfl_up(sc, off);
            if (tid >= off) sc += v;
        }
        const int eb = sc - quad;      // exclusive prefix of quad
        cur[i0]     = eb;
        cur[i0 + 1] = eb + c0;
        cur[i0 + 2] = eb + c0 + c1;
        cur[i0 + 3] = eb + c0 + c1 + c2;
        scn[i0]     = eb + c0;         // inclusive
        scn[i0 + 1] = eb + c0 + c1;
        scn[i0 + 2] = eb + c0 + c1 + c2;
        scn[i0 + 3] = eb + quad;
    }
    __syncthreads();

    for (int i = tid; i < len; i += 1024) {
        const unsigned e = sp[i];
        const int r = atomicAdd(&cur[e & (CSIZE - 1)], 1);
        order[r] = (e >> CBITS) << 7;   // src * 128 = byte offset into x8
    }
    __syncthreads();

    // ---- gather phase ----
    const int lane = tid & 63;
    const int wave = tid >> 6;       // 0..15
    const int ns   = lane >> 3;      // node slot 0..7
    const int c4   = lane & 7;       // uint4 column: channels c4*16 .. c4*16+15
    const unsigned chb = (unsigned)c4 * 16;

    for (int base = wave * 8; base < nn; base += 128) {
        const int nl = base + ns;
        int deg = 0, beg = 0;
        if (nl < nn) { deg = degh[nl]; beg = scn[nl] - deg; }
        f32x2 a[8] = {}, b[8] = {};
        int i = 0;
        for (; i + 4 <= deg; i += 4) {
            const unsigned o0 = order[beg + i];
            const unsigned o1 = order[beg + i + 1];
            const unsigned o2 = order[beg + i + 2];
            const unsigned o3 = order[beg + i + 3];
            uint4 v0 = *(const uint4*)(x8 + (o0 + chb));
            uint4 v1 = *(const uint4*)(x8 + (o1 + chb));
            uint4 v2 = *(const uint4*)(x8 + (o2 + chb));
            uint4 v3 = *(const uint4*)(x8 + (o3 + chb));
            acc16(a, v0); acc16(b, v1); acc16(a, v2); acc16(b, v3);
        }
        if (i < deg) {
            uint4 v = *(const uint4*)(x8 + (order[beg + i] + chb));
            acc16(a, v); ++i;
        }
        if (i < deg) {
            uint4 v = *(const uint4*)(x8 + (order[beg + i] + chb));
            acc16(b, v); ++i;
        }
        if (i < deg) {
            uint4 v = *(const uint4*)(x8 + (order[beg + i] + chb));
            acc16(a, v); ++i;
        }
        if (nl < nn) {
            const float rdiv = 1.0f / fmaxf((float)deg, 1.0f);
            unsigned w[8];
            #pragma unroll
            for (int j = 0; j < 8; ++j) {
                const f32x2 s = a[j] + b[j];
                w[j] = (unsigned)f2bf(s.x * rdiv) | ((unsigned)f2bf(s.y * rdiv) << 16);
            }
            unsigned short* dst = aggb + (long)(nbase + nl) * 128 + c4 * 16;
            *(uint4*)dst       = make_uint4(w[0], w[1], w[2], w[3]);
            *(uint4*)(dst + 8) = make_uint4(w[4], w[5], w[6], w[7]);
        }
    }
}

// GEMM v4: T3+T4 pipelined M-loop, 512 resident blocks (2/CU), 4-deep LDS ring
// (4 x 16 KB = 64 KB), counted s_waitcnt vmcnt (never 0 in steady state), ONE
// raw s_barrier per tile, B + bias hoisted to registers once per block, pool
// accumulated in registers with a single atomic flush. NO in-kernel grid sync
// (round 7: per-block __threadfence + done-counter cost ~25us).
__global__ __launch_bounds__(256, 2)
void gemm_pool(const unsigned short* __restrict__ xb, const unsigned short* __restrict__ aggb,
               const unsigned short* __restrict__ Bsw, const float* __restrict__ bias2,
               float* __restrict__ pooled_pad, int M, int NT) {
    __shared__ unsigned short As[4 * 32 * 256];   // 64 KB: 4 bufs x (32 rows x 512 B)
    const int tid  = threadIdx.x;
    const int lane = tid & 63;
    const int wn2  = tid >> 6;        // wave = 64-col group 0..3
    const int lrow = lane & 15;
    const int quad = lane >> 4;
    const int bid  = blockIdx.x;
    const int GRID = gridDim.x;
    const int nt   = (NT - bid + GRID - 1) / GRID;   // tiles for this block
    if (nt <= 0) return;

    // ---- B frags (32 x uint4 = 128 VGPR) + bias, once per block (L2-hot) ----
    uint4 bb[8][4];
    #pragma unroll
    for (int kk = 0; kk < 8; ++kk)
        #pragma unroll
        for (int t = 0; t < 4; ++t)
            bb[kk][t] = *(const uint4*)&Bsw[((((long)kk * 4 + wn2) * 4 + t) * 64 + lane) * 8];
    float bv[4];
    #pragma unroll
    for (int t = 0; t < 4; ++t) bv[t] = bias2[wn2 * 64 + t * 16 + lrow];

    // staging: thread covers (row%8 = rw, LDS chunk cl), source chunk cl^rw
    const int cl = tid & 31;
    const int rw = tid >> 5;
    const int cs = cl ^ rw;
    const unsigned short* sbase = (cs < 16) ? (xb + (long)cs * 8)
                                            : (aggb + (long)(cs - 16) * 8);
    char* lbase = (char*)As + rw * 512 + cl * 16;

    auto STAGE = [&](int p) {
        const long trow = ((long)bid + (long)p * GRID) * 32;
        char* ld = lbase + (p & 3) * 16384;
        #pragma unroll
        for (int s = 0; s < 4; ++s)
            g2lds16(sbase + (trow + s * 8 + rw) * 128, ld + s * 4096);
    };

    #pragma unroll
    for (int p = 0; p < 3; ++p) if (p < nt) STAGE(p);

    float ps[4] = {0.f, 0.f, 0.f, 0.f};

    for (int p = 0; p < nt; ++p) {
        const int rem = nt - 1 - p;
        if (rem >= 2)      asm volatile("s_waitcnt vmcnt(8)" ::: "memory");
        else if (rem == 1) asm volatile("s_waitcnt vmcnt(4)" ::: "memory");
        else               asm volatile("s_waitcnt vmcnt(0)" ::: "memory");
        __builtin_amdgcn_s_barrier();
        if (p + 3 < nt) STAGE(p + 3);   // 12 wave-loads in flight during compute

        const char* Ab = (const char*)As + (p & 3) * 16384;
        f32x4 acc[2][4] = {};
        #pragma unroll
        for (int kk = 0; kk < 8; ++kk) {
            uint4 aC[2];
            #pragma unroll
            for (int i = 0; i < 2; ++i) {
                const int r = i * 16 + lrow;   // r&7 == lrow&7
                aC[i] = *(const uint4*)(Ab + r * 512 + (((kk * 4 + quad) ^ (lrow & 7)) * 16));
            }
            #pragma unroll
            for (int i = 0; i < 2; ++i)
                #pragma unroll
                for (int t = 0; t < 4; ++t)
                    acc[i][t] = __builtin_amdgcn_mfma_f32_16x16x32_bf16(
                        *(bf16x8*)&aC[i], *(bf16x8*)&bb[kk][t], acc[i][t], 0, 0, 0);
        }

        // bias + ReLU + masked row-sum, accumulated in registers across tiles
        const long trow = ((long)bid + (long)p * GRID) * 32;
        #pragma unroll
        for (int t = 0; t < 4; ++t) {
            float s = 0.f;
            #pragma unroll
            for (int i = 0; i < 2; ++i) {
                const long rbase = trow + i * 16 + quad * 4;
                #pragma unroll
                for (int r = 0; r < 4; ++r) {
                    float h = fmaxf(acc[i][t][r] + bv[t], 0.f);
                    if (rbase + r < M) s += h;
                }
            }
            ps[t] += s;
        }
    }

    // single pooled flush per block
    #pragma unroll
    for (int t = 0; t < 4; ++t) {
        ps[t] += __shfl_xor(ps[t], 16);
        ps[t] += __shfl_xor(ps[t], 32);
        if (quad == 0)
            atomicAdd(&pooled_pad[(wn2 * 64 + t * 16 + lrow) * 16], ps[t]);
    }
}

// pooled -> MLP head -> log_softmax. One block, 256 threads.
__global__ __launch_bounds__(256)
void head_kernel(const float* __restrict__ pooled_pad,
                 const float* __restrict__ W1, const float* __restrict__ b1,
                 const float* __restrict__ W2, const float* __restrict__ b2,
                 float* __restrict__ out, float invM) {
    __shared__ float pooled_s[256];
    __shared__ float z1_s[256];
    __shared__ float z2_s[10];
    const int j = threadIdx.x;

    pooled_s[j] = pooled_pad[j * 16] * invM;
    __syncthreads();

    const float4* w4 = (const float4*)(W1 + (long)j * 256);
    float sx = 0.f, sy = 0.f, sz = 0.f, sw = 0.f;
    #pragma unroll 8
    for (int k = 0; k < 64; ++k) {
        float4 w = w4[k];
        float4 p = *(const float4*)&pooled_s[k * 4];
        sx += w.x * p.x; sy += w.y * p.y; sz += w.z * p.z; sw += w.w * p.w;
    }
    z1_s[j] = fmaxf(b1[j] + sx + sy + sz + sw, 0.f);
    __syncthreads();

    if (j < 160) {
        const int c = j >> 4, q = j & 15;
        float s = 0.f;
        for (int k = q; k < 256; k += 16) s += W2[c * 256 + k] * z1_s[k];
        #pragma unroll
        for (int off = 8; off >= 1; off >>= 1) s += __shfl_down(s, off, 16);
        if (q == 0) z2_s[c] = s + b2[c];
    }
    __syncthreads();

    if (j == 0) {
        float mx = z2_s[0];
        for (int c = 1; c < 10; ++c) mx = fmaxf(mx, z2_s[c]);
        float se = 0.f;
        for (int c = 0; c < 10; ++c) se += expf(z2_s[c] - mx);
        const float ls = logf(se);
        for (int c = 0; c < 10; ++c) out[c] = z2_s[c] - mx - ls;
    }
}

extern "C" void kernel_launch(void* const* d_in, const int* in_sizes, int n_in,
                              void* d_out, int out_size, void* d_ws, size_t ws_size,
                              hipStream_t stream) {
    const float* x    = (const float*)d_in[0];
    const void*  ei   = d_in[1];
    const float* Wl   = (const float*)d_in[2];
    const float* Wr   = (const float*)d_in[3];
    const float* bias = (const float*)d_in[4];
    const float* W1   = (const float*)d_in[5];
    const float* b1   = (const float*)d_in[6];
    const float* W2   = (const float*)d_in[7];
    const float* b2   = (const float*)d_in[8];
    float* out = (float*)d_out;

    const int M = in_sizes[0] / D_IN;        // 100000 nodes
    const int E = in_sizes[1] / 2;           // 1.6M edges
    const int L = in_sizes[4] / D_HID;       // 3 layers
    const int NMB = (M + 127) / 128;         // 128-row pad granules
    const long Mpad = (long)NMB * 128;       // row-padded region size (GEMM OOB-safe)
    const int NCB = (M + CSIZE - 1) / CSIZE; // buckets (391)
    const int NB1 = (E + EPB - 1) / EPB;     // binning blocks (391)
    const int NT  = (M + 31) / 32;           // gemm 32-row tiles (3125)
    const int NG  = (NT < 512) ? NT : 512;   // resident grid: 2 blocks/CU

    // Only the LAST layer matters (h is overwritten each loop iteration).
    const float* Wl2   = Wl + (long)(L - 1) * D_HID * D_IN;
    const float* Wr2   = Wr + (long)(L - 1) * D_HID * D_IN;
    const float* bias2 = bias + (long)(L - 1) * D_HID;

    // workspace: xb[Mpad*128]bf16 | aggb[Mpad*128]bf16 | x8[Mpad*128]u8 | Bsw[256*256]bf16 |
    //            pooled_pad[256*16]f | gcur[NCB*16]i | segc[NCB*CCAP]u
    //            (pad rows of xb/aggb are garbage; GEMM masks rows >= M)
    unsigned short* xb   = (unsigned short*)d_ws;
    unsigned short* aggb = xb + Mpad * D_IN;
    unsigned char*  x8   = (unsigned char*)(aggb + Mpad * D_IN);
    unsigned short* Bsw  = (unsigned short*)(x8 + Mpad * D_IN);
    float* pooled_pad    = (float*)(Bsw + 256 * 256);
    int*      gcur       = (int*)(pooled_pad + 256 * 16);
    unsigned* segc       = (unsigned*)(gcur + (long)NCB * 16);

    const long n16 = (long)M * 8;            // 16-float chunks of x
    const int NXB2 = (int)((n16 + 511) / 512);

    // zero pooled_pad + gcur in one contiguous memset (graph-capturable)
    hipMemsetAsync(pooled_pad, 0, 256 * 16 * 4 + (size_t)NCB * 16 * 4, stream);

    prep_bin<<<NB1 + 16 + NXB2, 512, 0, stream>>>(x, xb, x8, Wr2, Wl2, Bsw,
                                                  ei, gcur, segc, n16, NB1, E, NCB);
    refine_gather<<<NCB, 1024, 0, stream>>>(gcur, segc, x8, aggb, M);

    gemm_pool<<<NG, 256, 0, stream>>>(xb, aggb, Bsw, bias2, pooled_pad, M, NT);

    head_kernel<<<1, 256, 0, stream>>>(pooled_pad, W1, b1, W2, b2, out, 1.0f / (float)M);
}